// Round 9
// baseline (40.069 us; speedup 1.0000x reference)
//
#include <hip/hip_runtime.h>

// YOLO loss. B=32, H=W=32, A=9, C=80, T=50, NET=512.
// Stage 1: per-wave global->LDS DMA (width=16), 16 cells/wave, linear LDS.
// 4 lanes cooperate per cell (R3's verified compute, two-pass LSE).
// NO __syncthreads, NO atomics: per-wave tables + per-wave vmcnt fence;
// per-wave partial stored to ws[4*block+wid]. Stage 2 sums 576 per batch.

constexpr int NT   = 50;
constexpr int SPAN = 64 * 85;   // 5440 floats per array per block

#define G2L(gp, lp) __builtin_amdgcn_global_load_lds(                      \
    (const __attribute__((address_space(1))) void*)(gp),                   \
    (__attribute__((address_space(3))) void*)(lp), 16, 0, 0)

typedef __attribute__((ext_vector_type(4))) float f4;

__global__ __launch_bounds__(256) void yolo_loss_kernel(
    const float* __restrict__ y_pred,     // (B,H,W,A,85) flat
    const float* __restrict__ y_true,     // (B,H,W,A,85)
    const float* __restrict__ true_boxes, // (B,50,4)
    const float* __restrict__ anchors,    // (9,2)
    float* __restrict__ ws)               // (18432,) wave partials
{
    __shared__ float s_pred[SPAN];        // 21760 B
    __shared__ float s_true[SPAN];        // 21760 B
    __shared__ f4    s_box[4][NT];        // per-wave {minx,maxx,miny,maxy}
    __shared__ float s_area[4][NT];       // per-wave areas

    const int tid  = threadIdx.x;
    const int lane = tid & 63;
    const int wid  = tid >> 6;

    const int cell0 = blockIdx.x * 64;    // 64 cells per block, same batch b
    const int b     = cell0 / 9216;

    // ---- per-wave DMA: wave wid copies its own 1360-float slice of each
    //      array. 5440 B = 5*1024 + 320. LDS dest wave-uniform; HW adds
    //      lane*16. Global src 16B-aligned (cell0*340 + wid*5440 + lane*16).
    {
        const size_t gbase = (size_t)cell0 * 85 + (size_t)wid * 1360 + (size_t)lane * 4;
        const float* gp = y_pred + gbase;
        const float* gt = y_true + gbase;
        float* lp = s_pred + wid * 1360;  // wave-uniform
        float* lt = s_true + wid * 1360;
        #pragma unroll
        for (int k = 0; k < 5; ++k) {
            G2L(gp + k * 256, lp + k * 256);
            G2L(gt + k * 256, lt + k * 256);
        }
        if (lane < 20) {                  // 320-B tail
            G2L(gp + 5 * 256, lp + 5 * 256);
            G2L(gt + 5 * 256, lt + 5 * 256);
        }
    }

    // ---- per-wave IoU table (lanes 0..49 of THIS wave write it) ----
    if (lane < NT) {
        f4 tb;
        __builtin_memcpy(&tb, true_boxes + ((size_t)b * NT + lane) * 4, 16);
        const float tx = tb[0] * (1.0f / 32.0f);
        const float ty = tb[1] * (1.0f / 32.0f);
        const float tw = tb[2] * (1.0f / 512.0f);
        const float th = tb[3] * (1.0f / 512.0f);
        f4 e;
        e[0] = tx - tw * 0.5f;  e[1] = tx + tw * 0.5f;
        e[2] = ty - th * 0.5f;  e[3] = ty + th * 0.5f;
        s_box[wid][lane]  = e;
        s_area[wid][lane] = tw * th;
    }

    // wave-local fence: DMA (vmcnt) + table ds_writes (lgkmcnt) complete
    // before any LDS read below. No block barrier needed: all LDS use is
    // wave-private.
    asm volatile("s_waitcnt vmcnt(0) lgkmcnt(0)" ::: "memory");
    __builtin_amdgcn_sched_barrier(0);

    // ---- compute: 4 lanes per cell ----
    const int s = tid & 3;
    const int g = tid >> 2;               // 0..63; wave wid covers 16wid..16wid+15

    const int cell  = cell0 + g;
    const int local = cell - b * 9216;
    const int a = local % 9;
    const int w = (local / 9) % 32;
    const int h = local / 288;

    const float* cp = s_pred + g * 85;
    const float* ct = s_true + g * 85;

    // box fields: broadcast reads (4 lanes of a group hit same address)
    const float p0 = cp[0], p1 = cp[1], p2 = cp[2], p3 = cp[3], p4 = cp[4];
    const float t0 = ct[0], t1 = ct[1], t2 = ct[2], t3 = ct[3], t4 = ct[4];

    const float aw = anchors[a * 2 + 0];
    const float ah = anchors[a * 2 + 1];

    const float sig0  = 1.0f / (1.0f + __expf(-p0));
    const float sig1  = 1.0f / (1.0f + __expf(-p1));
    const float predx = (float)w + sig0;
    const float predy = (float)h + sig1;
    const float pconf = 1.0f / (1.0f + __expf(-p4));

    const float px = predx * (1.0f / 32.0f);
    const float py = predy * (1.0f / 32.0f);
    const float pw = __expf(p2) * aw * (1.0f / 512.0f);
    const float ph = __expf(p3) * ah * (1.0f / 512.0f);
    const float pminx = px - pw * 0.5f, pmaxx = px + pw * 0.5f;
    const float pminy = py - ph * 0.5f, pmaxy = py + ph * 0.5f;
    const float parea = pw * ph;

    // ---- IoU ignore flag, 12-13 boxes per lane; OR across group ----
    // best_iou >= 0.5  <=>  exists t: 2*inter >= union (union > 0 always)
    int ig = 0;
    #pragma unroll
    for (int i = 0; i < 13; ++i) {
        const int box = i * 4 + s;
        if (box < NT) {
            const f4 e = s_box[wid][box];
            float iw = fminf(pmaxx, e[1]) - fmaxf(pminx, e[0]);
            float ih = fminf(pmaxy, e[3]) - fmaxf(pminy, e[2]);
            iw = fmaxf(iw, 0.0f);
            ih = fmaxf(ih, 0.0f);
            float inter = iw * ih;
            float uni   = parea + s_area[wid][box] - inter;
            ig |= (2.0f * inter >= uni) ? 1 : 0;
        }
    }
    ig |= __shfl_xor(ig, 1);
    ig |= __shfl_xor(ig, 2);

    // ---- classes: lane s owns floats f = 4j+s (classes are f>=5).
    //      Pass A: pred to regs, argmax(true) carrying pred, max(pred).
    //      Pass B: sum exp(pred - max), 4 accumulators. ----
    float pv[21];
    float tmax = -1e30f, p_at = 0.0f, pmax = -1e30f;
    #pragma unroll
    for (int j = 0; j < 21; ++j) {
        const int f = 4 * j + s;
        const float pc = cp[f];
        const float tc = ct[f];
        pv[j] = pc;
        const bool cls = (f >= 5);
        const float tcm = cls ? tc : -1e30f;
        if (tcm > tmax) { tmax = tcm; p_at = pc; }
        pmax = fmaxf(pmax, cls ? pc : -1e30f);
    }
    float pv84 = -1e30f, t84m = -1e30f;
    if (s == 0) { pv84 = cp[84]; t84m = ct[84]; }
    if (t84m > tmax) { tmax = t84m; p_at = pv84; }
    pmax = fmaxf(pmax, pv84);

    #pragma unroll
    for (int d = 1; d <= 2; d <<= 1) {
        const float ot = __shfl_xor(tmax, d);
        const float op = __shfl_xor(p_at, d);
        if (ot > tmax) { tmax = ot; p_at = op; }
        pmax = fmaxf(pmax, __shfl_xor(pmax, d));
    }

    float acc[4] = {0.0f, 0.0f, 0.0f, 0.0f};
    #pragma unroll
    for (int j = 0; j < 21; ++j) {
        const int f = 4 * j + s;
        float e = __expf(pv[j] - pmax);
        if (f < 5) e = 0.0f;
        acc[j & 3] += e;
    }
    if (s == 0) acc[1] += __expf(pv84 - pmax);
    float sum = (acc[0] + acc[1]) + (acc[2] + acc[3]);
    sum += __shfl_xor(sum, 1);
    sum += __shfl_xor(sum, 2);
    const float ce = (pmax + __logf(sum)) - p_at;

    // ---- deltas (lane s==0 holds the cell's partial) ----
    const float om  = t4;
    const float ew  = __expf(t2) * aw * (1.0f / 512.0f);
    const float eh  = __expf(t3) * ah * (1.0f / 512.0f);
    const float whs = 2.0f - ew * eh;

    const float xyd0 = om * (predx - t0) * whs;
    const float xyd1 = om * (predy - t1) * whs;
    const float whd0 = om * (p2 - t2) * whs;
    const float whd1 = om * (p3 - t3) * whs;
    const float cd   = om * (pconf - t4) * 5.0f + (1.0f - om) * (ig ? 0.0f : pconf);

    float partial = xyd0 * xyd0 + xyd1 * xyd1 + whd0 * whd0 + whd1 * whd1 +
                    cd * cd + om * ce;
    partial = (s == 0) ? partial : 0.0f;

    // ---- wave reduction, plain store (no atomic, no barrier) ----
    #pragma unroll
    for (int off = 32; off > 0; off >>= 1)
        partial += __shfl_down(partial, off);
    if (lane == 0)
        ws[blockIdx.x * 4 + wid] = partial;
}

// Stage 2: one wave per batch sums its 576 wave-partials.
__global__ __launch_bounds__(64) void yolo_reduce_kernel(
    const float* __restrict__ ws,   // (18432,) = (32, 576)
    float* __restrict__ out)        // (B,)
{
    const int b    = blockIdx.x;
    const int lane = threadIdx.x;
    const float* p = ws + b * 576;

    float v = 0.0f;
    #pragma unroll
    for (int k = 0; k < 9; ++k) v += p[lane + 64 * k];
    #pragma unroll
    for (int off = 32; off > 0; off >>= 1)
        v += __shfl_down(v, off);
    if (lane == 0) out[b] = v;
}

extern "C" void kernel_launch(void* const* d_in, const int* in_sizes, int n_in,
                              void* d_out, int out_size, void* d_ws, size_t ws_size,
                              hipStream_t stream) {
    // setup_inputs order: input_image (unused), y_pred, y_true, true_boxes, anchors
    const float* y_pred     = (const float*)d_in[1];
    const float* y_true     = (const float*)d_in[2];
    const float* true_boxes = (const float*)d_in[3];
    const float* anchors    = (const float*)d_in[4];
    float* out = (float*)d_out;
    float* ws  = (float*)d_ws;   // 18432 floats; fully written before read

    dim3 grid(294912 / 64);      // 4608 blocks, 16 cells per wave
    yolo_loss_kernel<<<grid, 256, 0, stream>>>(y_pred, y_true, true_boxes, anchors, ws);
    yolo_reduce_kernel<<<32, 64, 0, stream>>>(ws, out);
}

// Round 10
// 38.431 us; speedup vs baseline: 1.0426x; 1.0426x over previous
//
#include <hip/hip_runtime.h>

// YOLO loss. B=32, H=W=32, A=9, C=80, T=50, NET=512.
// R8 structure (best: 38us) + VALU cuts:
//  - two-pass LSE (21 independent exps) instead of online (42 serial exps)
//  - packed f4 IoU table + per-wave tables, NO __syncthreads anywhere
//  - per-wave partial -> plain store (no atomics; R8's proven fix)
// 4 lanes/cell, lane s owns floats idx=4j+s. 4608 blocks x 256. Stage 2
// sums 576 wave-partials per batch.

constexpr int NT = 50;
typedef __attribute__((ext_vector_type(4))) float f4;

__global__ __launch_bounds__(256) void yolo_loss_kernel(
    const float* __restrict__ y_pred,     // (B,H,W,A,85) flat
    const float* __restrict__ y_true,     // (B,H,W,A,85)
    const float* __restrict__ true_boxes, // (B,50,4)
    const float* __restrict__ anchors,    // (9,2)
    float* __restrict__ ws)               // (18432,) wave partials
{
    __shared__ f4    s_box[4][NT];        // per-wave {minx,maxx,miny,maxy}
    __shared__ float s_area[4][NT];       // per-wave areas
    __shared__ float s_anch[4][18];       // per-wave anchor copy

    const int tid  = threadIdx.x;
    const int lane = tid & 63;
    const int wid  = tid >> 6;

    const int cell0 = blockIdx.x * 64;    // 64 cells per block, same batch b
    const int b     = cell0 / 9216;

    const int s  = tid & 3;               // slice within cell group
    const int g  = tid >> 2;              // cell within block: 0..63
    const int gb = lane & ~3;             // group base lane in wave

    const int cell  = cell0 + g;
    const int local = cell - b * 9216;
    const int a = local % 9;
    const int w = (local / 9) % 32;
    const int h = local / 288;

    const size_t base = (size_t)cell * 85 + s;
    const float* P = y_pred + base;
    const float* T = y_true + base;

    // ---- R8's proven coalesced interleaved loads: lane s owns idx=4j+s ----
    float pv[21], tv[21];
    #pragma unroll
    for (int j = 0; j < 21; ++j) pv[j] = P[4 * j];
    #pragma unroll
    for (int j = 0; j < 21; ++j) tv[j] = T[4 * j];
    float p84 = 0.0f, t84 = 0.0f;
    if (s == 0) { p84 = P[84]; t84 = T[84]; }   // idx 84, s=0 only

    // ---- per-wave tables (wave-local fence only; no block barrier) ----
    if (lane < NT) {
        f4 tb;
        __builtin_memcpy(&tb, true_boxes + ((size_t)b * NT + lane) * 4, 16);
        const float tx = tb[0] * (1.0f / 32.0f);
        const float ty = tb[1] * (1.0f / 32.0f);
        const float tw = tb[2] * (1.0f / 512.0f);
        const float th = tb[3] * (1.0f / 512.0f);
        f4 e;
        e[0] = tx - tw * 0.5f;  e[1] = tx + tw * 0.5f;
        e[2] = ty - th * 0.5f;  e[3] = ty + th * 0.5f;
        s_box[wid][lane]  = e;
        s_area[wid][lane] = tw * th;
    }
    if (lane < 18) s_anch[wid][lane] = anchors[lane];

    asm volatile("s_waitcnt lgkmcnt(0)" ::: "memory");  // wave-local LDS fence
    __builtin_amdgcn_sched_barrier(0);

    // ---- gather box fields via shuffles (idx n on lane gb+n v[0]; idx4 on
    //      lane gb+0 v[1]) ----
    const float p0 = __shfl(pv[0], gb + 0);
    const float p1 = __shfl(pv[0], gb + 1);
    const float p2 = __shfl(pv[0], gb + 2);
    const float p3 = __shfl(pv[0], gb + 3);
    const float p4 = __shfl(pv[1], gb + 0);
    const float t0 = __shfl(tv[0], gb + 0);
    const float t1 = __shfl(tv[0], gb + 1);
    const float t2 = __shfl(tv[0], gb + 2);
    const float t3 = __shfl(tv[0], gb + 3);
    const float t4 = __shfl(tv[1], gb + 0);

    const float aw = s_anch[wid][a * 2 + 0];
    const float ah = s_anch[wid][a * 2 + 1];

    // ---- geometry (redundant on 4 lanes — cheap) ----
    const float sig0  = 1.0f / (1.0f + __expf(-p0));
    const float sig1  = 1.0f / (1.0f + __expf(-p1));
    const float predx = (float)w + sig0;
    const float predy = (float)h + sig1;
    const float pconf = 1.0f / (1.0f + __expf(-p4));

    const float px = predx * (1.0f / 32.0f);
    const float py = predy * (1.0f / 32.0f);
    const float pw = __expf(p2) * aw * (1.0f / 512.0f);
    const float ph = __expf(p3) * ah * (1.0f / 512.0f);
    const float pminx = px - pw * 0.5f, pmaxx = px + pw * 0.5f;
    const float pminy = py - ph * 0.5f, pmaxy = py + ph * 0.5f;
    const float parea = pw * ph;

    // ---- IoU ignore flag: packed f4 table, 12-13 boxes per lane ----
    // best_iou >= 0.5  <=>  exists t: 2*inter >= union (union > 0 always)
    int ig = 0;
    #pragma unroll
    for (int i = 0; i < 13; ++i) {
        const int box = i * 4 + s;
        if (box < NT) {
            const f4 e = s_box[wid][box];
            float iw = fminf(pmaxx, e[1]) - fmaxf(pminx, e[0]);
            float ih = fminf(pmaxy, e[3]) - fmaxf(pminy, e[2]);
            iw = fmaxf(iw, 0.0f);
            ih = fmaxf(ih, 0.0f);
            const float inter = iw * ih;
            const float uni   = parea + s_area[wid][box] - inter;
            ig |= (2.0f * inter >= uni) ? 1 : 0;
        }
    }
    ig |= __shfl_xor(ig, 1);
    ig |= __shfl_xor(ig, 2);

    // ---- classes pass A: argmax(true) carrying pred + max(pred).
    //      cls mask is compile-time-constant for j>=2 (f=4j+s>=8>5). ----
    float tmax = -1e30f, p_at = 0.0f, pmax = -1e30f;
    #pragma unroll
    for (int j = 0; j < 21; ++j) {
        const bool cls = (j >= 2) || (j == 1 && s != 0) || (4 * j + s >= 5);
        const float tcm = cls ? tv[j] : -1e30f;
        const float pcm = cls ? pv[j] : -1e30f;
        if (tcm > tmax) { tmax = tcm; p_at = pv[j]; }
        pmax = fmaxf(pmax, pcm);
    }
    {   // tail idx 84 (s==0 only)
        const float tcm = (s == 0) ? t84 : -1e30f;
        if (tcm > tmax) { tmax = tcm; p_at = p84; }
        pmax = fmaxf(pmax, (s == 0) ? p84 : -1e30f);
    }
    // combine across the 4 lanes of the group
    #pragma unroll
    for (int d = 1; d <= 2; d <<= 1) {
        const float ot = __shfl_xor(tmax, d);
        const float op = __shfl_xor(p_at, d);
        if (ot > tmax) { tmax = ot; p_at = op; }
        pmax = fmaxf(pmax, __shfl_xor(pmax, d));
    }

    // ---- classes pass B: 21 independent exps, 4 accumulator streams ----
    float acc[4] = {0.0f, 0.0f, 0.0f, 0.0f};
    #pragma unroll
    for (int j = 0; j < 21; ++j) {
        const bool cls = (j >= 2) || (j == 1 && s != 0) || (4 * j + s >= 5);
        const float e = __expf(pv[j] - pmax);
        acc[j & 3] += cls ? e : 0.0f;
    }
    {
        const float e = __expf(p84 - pmax);
        acc[1] += (s == 0) ? e : 0.0f;
    }
    float sum = (acc[0] + acc[1]) + (acc[2] + acc[3]);
    sum += __shfl_xor(sum, 1);
    sum += __shfl_xor(sum, 2);
    const float ce = (pmax + __logf(sum)) - p_at;

    // ---- deltas (lane s==0 holds the cell's partial) ----
    const float om  = t4;
    const float ew  = __expf(t2) * aw * (1.0f / 512.0f);
    const float eh  = __expf(t3) * ah * (1.0f / 512.0f);
    const float whs = 2.0f - ew * eh;

    const float xyd0 = om * (predx - t0) * whs;
    const float xyd1 = om * (predy - t1) * whs;
    const float whd0 = om * (p2 - t2) * whs;
    const float whd1 = om * (p3 - t3) * whs;
    const float cd   = om * (pconf - t4) * 5.0f + (1.0f - om) * (ig ? 0.0f : pconf);

    float partial = xyd0 * xyd0 + xyd1 * xyd1 + whd0 * whd0 + whd1 * whd1 +
                    cd * cd + om * ce;
    partial = (s == 0) ? partial : 0.0f;

    // ---- wave reduction, plain store (no atomic, no barrier) ----
    #pragma unroll
    for (int off = 32; off > 0; off >>= 1)
        partial += __shfl_down(partial, off);
    if (lane == 0)
        ws[blockIdx.x * 4 + wid] = partial;
}

// Stage 2: one wave per batch sums its 576 wave-partials.
__global__ __launch_bounds__(64) void yolo_reduce_kernel(
    const float* __restrict__ ws,   // (18432,) = (32, 576)
    float* __restrict__ out)        // (B,)
{
    const int b    = blockIdx.x;
    const int lane = threadIdx.x;
    const float* p = ws + b * 576;

    float v = 0.0f;
    #pragma unroll
    for (int k = 0; k < 9; ++k) v += p[lane + 64 * k];
    #pragma unroll
    for (int off = 32; off > 0; off >>= 1)
        v += __shfl_down(v, off);
    if (lane == 0) out[b] = v;
}

extern "C" void kernel_launch(void* const* d_in, const int* in_sizes, int n_in,
                              void* d_out, int out_size, void* d_ws, size_t ws_size,
                              hipStream_t stream) {
    // setup_inputs order: input_image (unused), y_pred, y_true, true_boxes, anchors
    const float* y_pred     = (const float*)d_in[1];
    const float* y_true     = (const float*)d_in[2];
    const float* true_boxes = (const float*)d_in[3];
    const float* anchors    = (const float*)d_in[4];
    float* out = (float*)d_out;
    float* ws  = (float*)d_ws;   // 18432 floats; fully written before read

    dim3 grid(294912 / 64);      // 4608 blocks, 64 cells each
    yolo_loss_kernel<<<grid, 256, 0, stream>>>(y_pred, y_true, true_boxes, anchors, ws);
    yolo_reduce_kernel<<<32, 64, 0, stream>>>(ws, out);
}